// Round 7
// baseline (200.402 us; speedup 1.0000x reference)
//
#include <hip/hip_runtime.h>

#define HEADS 4
#define OUT_CH 16
#define CCH 64            // HEADS*OUT_CH
#define IN_CH 128
#define NEG_SLOPE 0.2f
#define GW 32             // k-slice per wave in the GEMM

typedef unsigned int   uint32;
typedef unsigned short u16;

__device__ __forceinline__ uint32 bf16_rne(float f) {
    uint32 u = __float_as_uint(f);
    return (u + 0x7fffu + ((u >> 16) & 1u)) >> 16;
}

// ---------------------------------------------------------------------------
// Zero kernel (replaces hipMemsetAsync graph node)
// ---------------------------------------------------------------------------
__global__ void k_zero(int* __restrict__ p, int n) {
    int i = blockIdx.x * 256 + threadIdx.x;
    if (i < n) p[i] = 0;
}

// ---------------------------------------------------------------------------
// GEMM: h[N][64] = x[N][128] @ w[128][64], output bf16.
// Block = 4 waves. Wave w owns k in [32w,32w+32): W slice = 32 VGPRs/lane.
// x slices are wave-uniform -> scalar loads. Partials through ONE LDS buffer
// with TWO barriers per 4-row batch (write -> bar -> read -> bar).
// ---------------------------------------------------------------------------
__global__ __launch_bounds__(256, 4) void gat_gemm(const float* __restrict__ x,
                                                   const float* __restrict__ w,
                                                   const float* __restrict__ att,
                                                   u16* __restrict__ h_bf,
                                                   float* __restrict__ d_i,
                                                   float* __restrict__ d_j,
                                                   int N, int nblocks) {
    __shared__ float part[4][4][64];   // [row][wave][lane]
    int t = threadIdx.x;
    int lane = t & 63;
    int wid = t >> 6;

    float wr[GW];
    #pragma unroll
    for (int j = 0; j < GW; ++j) wr[j] = w[(wid * GW + j) * CCH + lane];

    int head = lane >> 4, ch = lane & 15;
    float ai = att[head * (2 * OUT_CH) + ch];
    float aj = att[head * (2 * OUT_CH) + OUT_CH + ch];

    for (int rb = blockIdx.x * 4; rb < N; rb += nblocks * 4) {
        #pragma unroll
        for (int rr = 0; rr < 4; ++rr) {
            int r = rb + rr; if (r >= N) r = N - 1;
            const float* __restrict__ xp = x + (size_t)r * IN_CH + wid * GW;
            float a0 = 0.f, a1 = 0.f, a2 = 0.f, a3 = 0.f;
            #pragma unroll
            for (int j = 0; j < GW; j += 4) {
                a0 = fmaf(xp[j + 0], wr[j + 0], a0);
                a1 = fmaf(xp[j + 1], wr[j + 1], a1);
                a2 = fmaf(xp[j + 2], wr[j + 2], a2);
                a3 = fmaf(xp[j + 3], wr[j + 3], a3);
            }
            part[rr][wid][lane] = (a0 + a1) + (a2 + a3);
        }
        __syncthreads();

        int r = rb + wid; if (r >= N) r = N - 1;
        float acc = part[wid][0][lane] + part[wid][1][lane]
                  + part[wid][2][lane] + part[wid][3][lane];

        h_bf[(size_t)r * CCH + lane] = (u16)bf16_rne(acc);

        float si = acc * ai, sj = acc * aj;
        #pragma unroll
        for (int off = 1; off < 16; off <<= 1) {
            si += __shfl_xor(si, off);
            sj += __shfl_xor(sj, off);
        }
        if (ch == 0) {
            d_i[r * HEADS + head] = si;
            d_j[r * HEADS + head] = sj;
        }
        __syncthreads();   // protect next iteration's LDS writes
    }
}

// ---------------------------------------------------------------------------
// Count + rank: rank[e] = arrival order at dest c; deg histogram.
// ---------------------------------------------------------------------------
__global__ __launch_bounds__(256) void k_count_rank(const int* __restrict__ cols,
                                                    int* __restrict__ deg,
                                                    int* __restrict__ rank,
                                                    int E, int N) {
    int e = blockIdx.x * blockDim.x + threadIdx.x;
    if (e >= E + N) return;
    int c = (e < E) ? cols[e] : (e - E);
    rank[e] = atomicAdd(&deg[c], 1);
}

// ---------------------------------------------------------------------------
// Scan: block-local -> partials -> add
// ---------------------------------------------------------------------------
__global__ __launch_bounds__(256) void k_scan_blk(const int* __restrict__ deg,
                                                  int* __restrict__ offs,
                                                  int* __restrict__ partials, int N) {
    __shared__ int wsum[4];
    int t = threadIdx.x, lane = t & 63, wid = t >> 6;
    int base = blockIdx.x * 1024 + t * 4;
    int v0 = 0, v1 = 0, v2 = 0, v3 = 0;
    if (base + 3 < N) {
        int4 q = *(const int4*)(deg + base);
        v0 = q.x; v1 = q.y; v2 = q.z; v3 = q.w;
    } else {
        if (base     < N) v0 = deg[base];
        if (base + 1 < N) v1 = deg[base + 1];
        if (base + 2 < N) v2 = deg[base + 2];
        if (base + 3 < N) v3 = deg[base + 3];
    }
    int ts = v0 + v1 + v2 + v3;
    int sc = ts;
    #pragma unroll
    for (int off = 1; off < 64; off <<= 1) {
        int u = __shfl_up(sc, off);
        if (lane >= off) sc += u;
    }
    if (lane == 63) wsum[wid] = sc;
    __syncthreads();
    int wb = 0;
    for (int i = 0; i < wid; ++i) wb += wsum[i];
    int excl = wb + sc - ts;
    if (base     < N) offs[base]     = excl;
    if (base + 1 < N) offs[base + 1] = excl + v0;
    if (base + 2 < N) offs[base + 2] = excl + v0 + v1;
    if (base + 3 < N) offs[base + 3] = excl + v0 + v1 + v2;
    if (t == 255) partials[blockIdx.x] = wb + sc;
}

__global__ __launch_bounds__(64) void k_scan_part(int* __restrict__ partials, int NB) {
    int lane = threadIdx.x;
    int carry = 0;
    for (int b = 0; b < NB; b += 64) {
        int idx = b + lane;
        int v = (idx < NB) ? partials[idx] : 0;
        int sc = v;
        #pragma unroll
        for (int off = 1; off < 64; off <<= 1) {
            int u = __shfl_up(sc, off);
            if (lane >= off) sc += u;
        }
        if (idx < NB) partials[idx] = carry + sc - v;
        carry += __shfl(sc, 63);
    }
    if (lane == 0) partials[NB] = carry;
}

__global__ void k_scan_add(int* __restrict__ offs,
                           const int* __restrict__ partials, int N, int NB) {
    int i = blockIdx.x * 256 + threadIdx.x;
    if (i < N) offs[i] += partials[i >> 10];
    if (i == 0) offs[N] = partials[NB];
}

// ---------------------------------------------------------------------------
// Scatter + alpha: pos = offs[c] + rank[e]; softmax-over-heads alpha from
// d_i/d_j (L2-resident); pack {row, a01, a23} as one 16 B record.
// ---------------------------------------------------------------------------
__global__ __launch_bounds__(256) void k_scatter_alpha(const int* __restrict__ rows,
                                                       const int* __restrict__ cols,
                                                       const int* __restrict__ offs,
                                                       const int* __restrict__ rank,
                                                       const float* __restrict__ d_i,
                                                       const float* __restrict__ d_j,
                                                       uint4* __restrict__ sorted,
                                                       int E, int N) {
    int e = blockIdx.x * blockDim.x + threadIdx.x;
    if (e >= E + N) return;
    int r, c;
    if (e < E) { r = rows[e]; c = cols[e]; }
    else       { r = e - E;   c = r; }
    int pos = offs[c] + rank[e];

    float4 di4 = *(const float4*)(d_i + (size_t)r * HEADS);
    float4 dj4 = *(const float4*)(d_j + (size_t)c * HEADS);
    float l0 = di4.x + dj4.x, l1 = di4.y + dj4.y;
    float l2 = di4.z + dj4.z, l3 = di4.w + dj4.w;
    l0 = l0 > 0.f ? l0 : NEG_SLOPE * l0;
    l1 = l1 > 0.f ? l1 : NEG_SLOPE * l1;
    l2 = l2 > 0.f ? l2 : NEG_SLOPE * l2;
    l3 = l3 > 0.f ? l3 : NEG_SLOPE * l3;
    float m = fmaxf(fmaxf(l0, l1), fmaxf(l2, l3));
    float e0 = __expf(l0 - m), e1 = __expf(l1 - m);
    float e2 = __expf(l2 - m), e3 = __expf(l3 - m);
    float inv = 1.f / (e0 + e1 + e2 + e3);

    uint32 p01 = bf16_rne(e0 * inv) | (bf16_rne(e1 * inv) << 16);
    uint32 p23 = bf16_rne(e2 * inv) | (bf16_rne(e3 * inv) << 16);
    sorted[pos] = make_uint4((uint32)r, p01, p23, 0u);
}

// ---------------------------------------------------------------------------
// Accumulate: one wave per dest node. Record loads forced to the VECTOR
// path (asm uniformity-breaker) -> global_load_dwordx4 broadcast, no s_load.
// ---------------------------------------------------------------------------
__global__ __launch_bounds__(256) void k_accum(const int* __restrict__ offs,
                                               const uint4* __restrict__ sorted,
                                               const u16* __restrict__ h_bf,
                                               const float* __restrict__ bias,
                                               float* __restrict__ out, int N) {
    int node = blockIdx.x * 4 + (threadIdx.x >> 6);
    if (node >= N) return;
    int c = __builtin_amdgcn_readfirstlane(node);
    int lane = threadIdx.x & 63;
    int head = lane >> 4;

    int s = offs[c], e = offs[c + 1];
    float acc = 0.f;
    int i = s;
    for (; i + 1 < e; i += 2) {
        int i0 = i, i1 = i + 1;
        asm volatile("" : "+v"(i0));
        asm volatile("" : "+v"(i1));
        uint4 v0 = sorted[i0];
        uint4 v1 = sorted[i1];
        uint32 p0 = (head & 2) ? v0.z : v0.y;
        uint32 p1 = (head & 2) ? v1.z : v1.y;
        float a0 = (head & 1) ? __uint_as_float(p0 & 0xffff0000u)
                              : __uint_as_float(p0 << 16);
        float a1 = (head & 1) ? __uint_as_float(p1 & 0xffff0000u)
                              : __uint_as_float(p1 << 16);
        u16 hb0 = h_bf[(size_t)v0.x * CCH + lane];
        u16 hb1 = h_bf[(size_t)v1.x * CCH + lane];
        acc = fmaf(__uint_as_float((uint32)hb0 << 16), a0, acc);
        acc = fmaf(__uint_as_float((uint32)hb1 << 16), a1, acc);
    }
    if (i < e) {
        int i0 = i;
        asm volatile("" : "+v"(i0));
        uint4 v0 = sorted[i0];
        uint32 p0 = (head & 2) ? v0.z : v0.y;
        float a0 = (head & 1) ? __uint_as_float(p0 & 0xffff0000u)
                              : __uint_as_float(p0 << 16);
        u16 hb0 = h_bf[(size_t)v0.x * CCH + lane];
        acc = fmaf(__uint_as_float((uint32)hb0 << 16), a0, acc);
    }
    out[(size_t)c * CCH + lane] = acc + bias[lane];
}

extern "C" void kernel_launch(void* const* d_in, const int* in_sizes, int n_in,
                              void* d_out, int out_size, void* d_ws, size_t ws_size,
                              hipStream_t stream) {
    const float* x    = (const float*)d_in[0];
    const int*   ei   = (const int*)  d_in[1];
    const float* w    = (const float*)d_in[2];
    const float* att  = (const float*)d_in[3];
    const float* bias = (const float*)d_in[4];
    float* out = (float*)d_out;

    int N = in_sizes[0] / IN_CH;
    int E = in_sizes[1] / 2;
    const int* rows = ei;
    const int* cols = ei + E;
    int total_e = E + N;
    int NB = (N + 1023) / 1024;
    int Npad = (N + 3) & ~3;

    char* ws = (char*)d_ws;
    auto carve = [&](size_t bytes) {
        char* p = ws;
        ws += (bytes + 255) & ~(size_t)255;
        return p;
    };
    u16*   h_bf   = (u16*)  carve((size_t)N * CCH * 2);          // 6.4 MB
    float* di     = (float*)carve((size_t)N * HEADS * 4);        // 0.8 MB
    float* dj     = (float*)carve((size_t)N * HEADS * 4);        // 0.8 MB
    int*   deg    = (int*)  carve((size_t)Npad * 4);
    int*   offs   = (int*)  carve((size_t)(N + 1) * 4);
    int*   parts  = (int*)  carve((size_t)(NB + 1) * 4);
    int*   rank   = (int*)  carve((size_t)total_e * 4);          // 3.4 MB
    uint4* sorted = (uint4*)carve((size_t)total_e * 16);         // 13.6 MB

    const int NBLOCKS = 2048;

    k_zero<<<(Npad + 255) / 256, 256, 0, stream>>>(deg, Npad);
    k_count_rank<<<(total_e + 255) / 256, 256, 0, stream>>>(cols, deg, rank, E, N);
    k_scan_blk<<<NB, 256, 0, stream>>>(deg, offs, parts, N);
    k_scan_part<<<1, 64, 0, stream>>>(parts, NB);
    k_scan_add<<<(N + 255) / 256, 256, 0, stream>>>(offs, parts, N, NB);
    gat_gemm<<<NBLOCKS, 256, 0, stream>>>(x, w, att, h_bf, di, dj, N, NBLOCKS);
    k_scatter_alpha<<<(total_e + 255) / 256, 256, 0, stream>>>(rows, cols, offs, rank,
                                                               di, dj, sorted, E, N);
    k_accum<<<(N + 3) / 4, 256, 0, stream>>>(offs, sorted, h_bf, bias, out, N);
}

// Round 8
// 138.770 us; speedup vs baseline: 1.4441x; 1.4441x over previous
//
#include <hip/hip_runtime.h>

#define HEADS 4
#define OUT_CH 16
#define CCH 64            // HEADS*OUT_CH
#define IN_CH 128
#define NEG_SLOPE 0.2f

typedef unsigned int   uint32;
typedef unsigned short u16;
typedef __attribute__((ext_vector_type(8))) short short8;
typedef __attribute__((ext_vector_type(4))) float f32x4;

__device__ __forceinline__ uint32 bf16_rne(float f) {
    uint32 u = __float_as_uint(f);
    return (u + 0x7fffu + ((u >> 16) & 1u)) >> 16;
}

// ---------------------------------------------------------------------------
// Zero kernel
// ---------------------------------------------------------------------------
__global__ void k_zero(int* __restrict__ p, int n) {
    int i = blockIdx.x * 256 + threadIdx.x;
    if (i < n) p[i] = 0;
}

// ---------------------------------------------------------------------------
// MFMA GEMM: h_bf[N][64] = bf16( f32(x[N][128]) @ w[128][64] ).
// W staged once per block as bf16 wT[64][136] (transposed, padded).
// Wave-per-16-row-tile, grid-stride, 1-deep prefetch, no loop barriers.
// A-frag: lane reads x[rb+(lane&15)][kc*32+(lane>>4)*8 .. +8)  (2 float4)
// B-frag: wT[nt*16+(lane&15)][kc*32+(lane>>4)*8 .. +8)         (ds_read_b128)
// D: row=(lane>>4)*4+reg, col=nt*16+(lane&15)   [guide-verified layout]
// ---------------------------------------------------------------------------
__global__ __launch_bounds__(256) void gat_gemm_mfma(const float* __restrict__ x,
                                                     const float* __restrict__ w,
                                                     u16* __restrict__ h_bf,
                                                     int N, int nwaves) {
    __shared__ u16 wT[64 * 136];   // 17.4 KB
    int t = threadIdx.x, lane = t & 63;

    for (int i = t; i < IN_CH * CCH; i += 256) {
        int k = i >> 6, c = i & 63;
        wT[c * 136 + k] = (u16)bf16_rne(w[i]);
    }
    __syncthreads();

    short8 bfrag[4][4];
    {
        int col = lane & 15, g = (lane >> 4) * 8;
        #pragma unroll
        for (int nt = 0; nt < 4; ++nt)
            #pragma unroll
            for (int kc = 0; kc < 4; ++kc)
                bfrag[nt][kc] = *(const short8*)&wT[(nt * 16 + col) * 136 + kc * 32 + g];
    }

    int gw = blockIdx.x * 4 + (t >> 6);
    int ntiles = (N + 15) >> 4;
    int row0 = lane & 15, kg = (lane >> 4) * 8;

    float4 cur[8], nxt[8];

    auto LOAD = [&](int tile, float4* buf) {
        int r = tile * 16 + row0;
        if (r >= N) r = N - 1;
        const float* xp = x + (size_t)r * IN_CH + kg;
        #pragma unroll
        for (int kc = 0; kc < 4; ++kc) {
            buf[kc * 2]     = *(const float4*)(xp + kc * 32);
            buf[kc * 2 + 1] = *(const float4*)(xp + kc * 32 + 4);
        }
    };

    int tile = gw;
    if (tile < ntiles) LOAD(tile, cur);
    for (; tile < ntiles; tile += nwaves) {
        int tn = tile + nwaves;
        if (tn < ntiles) LOAD(tn, nxt);

        short8 af[4];
        #pragma unroll
        for (int kc = 0; kc < 4; ++kc) {
            float4 u = cur[kc * 2], v = cur[kc * 2 + 1];
            short8 s;
            s[0] = (short)bf16_rne(u.x); s[1] = (short)bf16_rne(u.y);
            s[2] = (short)bf16_rne(u.z); s[3] = (short)bf16_rne(u.w);
            s[4] = (short)bf16_rne(v.x); s[5] = (short)bf16_rne(v.y);
            s[6] = (short)bf16_rne(v.z); s[7] = (short)bf16_rne(v.w);
            af[kc] = s;
        }

        f32x4 acc[4] = {{0.f,0.f,0.f,0.f},{0.f,0.f,0.f,0.f},
                        {0.f,0.f,0.f,0.f},{0.f,0.f,0.f,0.f}};
        #pragma unroll
        for (int kc = 0; kc < 4; ++kc)
            #pragma unroll
            for (int nt = 0; nt < 4; ++nt)
                acc[nt] = __builtin_amdgcn_mfma_f32_16x16x32_bf16(
                    af[kc], bfrag[nt][kc], acc[nt], 0, 0, 0);

        int rb = tile * 16;
        #pragma unroll
        for (int nt = 0; nt < 4; ++nt)
            #pragma unroll
            for (int r = 0; r < 4; ++r) {
                int row = rb + (lane >> 4) * 4 + r;
                if (row < N)
                    h_bf[(size_t)row * CCH + nt * 16 + (lane & 15)] =
                        (u16)bf16_rne(acc[nt][r]);
            }

        #pragma unroll
        for (int i = 0; i < 8; ++i) cur[i] = nxt[i];
    }
}

// ---------------------------------------------------------------------------
// Per-(row,head) attention dots from h_bf: d_i = h·att_i, d_j = h·att_j.
// Thread idx = r*4+head reads 32 B contiguous -> perfectly coalesced.
// ---------------------------------------------------------------------------
__global__ __launch_bounds__(256) void k_dots(const u16* __restrict__ h_bf,
                                              const float* __restrict__ att,
                                              float* __restrict__ d_i,
                                              float* __restrict__ d_j, int N) {
    int idx = blockIdx.x * 256 + threadIdx.x;
    if (idx >= N * HEADS) return;
    int head = idx & 3;
    const u16* hp = h_bf + (size_t)(idx >> 2) * CCH + head * OUT_CH;
    const float* ap = att + head * (2 * OUT_CH);

    uint4 q0 = *(const uint4*)hp;
    uint4 q1 = *(const uint4*)(hp + 8);
    uint32 words[8] = {q0.x, q0.y, q0.z, q0.w, q1.x, q1.y, q1.z, q1.w};
    float si = 0.f, sj = 0.f;
    #pragma unroll
    for (int i = 0; i < 8; ++i) {
        float lo = __uint_as_float(words[i] << 16);
        float hi = __uint_as_float(words[i] & 0xffff0000u);
        si = fmaf(lo, ap[i * 2], si);      si = fmaf(hi, ap[i * 2 + 1], si);
        sj = fmaf(lo, ap[16 + i * 2], sj); sj = fmaf(hi, ap[16 + i * 2 + 1], sj);
    }
    d_i[idx] = si;
    d_j[idx] = sj;
}

// ---------------------------------------------------------------------------
// Count + rank
// ---------------------------------------------------------------------------
__global__ __launch_bounds__(256) void k_count_rank(const int* __restrict__ cols,
                                                    int* __restrict__ deg,
                                                    int* __restrict__ rank,
                                                    int E, int N) {
    int e = blockIdx.x * blockDim.x + threadIdx.x;
    if (e >= E + N) return;
    int c = (e < E) ? cols[e] : (e - E);
    rank[e] = atomicAdd(&deg[c], 1);
}

// ---------------------------------------------------------------------------
// Scan: block-local -> partials -> add
// ---------------------------------------------------------------------------
__global__ __launch_bounds__(256) void k_scan_blk(const int* __restrict__ deg,
                                                  int* __restrict__ offs,
                                                  int* __restrict__ partials, int N) {
    __shared__ int wsum[4];
    int t = threadIdx.x, lane = t & 63, wid = t >> 6;
    int base = blockIdx.x * 1024 + t * 4;
    int v0 = 0, v1 = 0, v2 = 0, v3 = 0;
    if (base + 3 < N) {
        int4 q = *(const int4*)(deg + base);
        v0 = q.x; v1 = q.y; v2 = q.z; v3 = q.w;
    } else {
        if (base     < N) v0 = deg[base];
        if (base + 1 < N) v1 = deg[base + 1];
        if (base + 2 < N) v2 = deg[base + 2];
        if (base + 3 < N) v3 = deg[base + 3];
    }
    int ts = v0 + v1 + v2 + v3;
    int sc = ts;
    #pragma unroll
    for (int off = 1; off < 64; off <<= 1) {
        int u = __shfl_up(sc, off);
        if (lane >= off) sc += u;
    }
    if (lane == 63) wsum[wid] = sc;
    __syncthreads();
    int wb = 0;
    for (int i = 0; i < wid; ++i) wb += wsum[i];
    int excl = wb + sc - ts;
    if (base     < N) offs[base]     = excl;
    if (base + 1 < N) offs[base + 1] = excl + v0;
    if (base + 2 < N) offs[base + 2] = excl + v0 + v1;
    if (base + 3 < N) offs[base + 3] = excl + v0 + v1 + v2;
    if (t == 255) partials[blockIdx.x] = wb + sc;
}

__global__ __launch_bounds__(64) void k_scan_part(int* __restrict__ partials, int NB) {
    int lane = threadIdx.x;
    int carry = 0;
    for (int b = 0; b < NB; b += 64) {
        int idx = b + lane;
        int v = (idx < NB) ? partials[idx] : 0;
        int sc = v;
        #pragma unroll
        for (int off = 1; off < 64; off <<= 1) {
            int u = __shfl_up(sc, off);
            if (lane >= off) sc += u;
        }
        if (idx < NB) partials[idx] = carry + sc - v;
        carry += __shfl(sc, 63);
    }
    if (lane == 0) partials[NB] = carry;
}

__global__ void k_scan_add(int* __restrict__ offs,
                           const int* __restrict__ partials, int N, int NB) {
    int i = blockIdx.x * 256 + threadIdx.x;
    if (i < N) offs[i] += partials[i >> 10];
    if (i == 0) offs[N] = partials[NB];
}

// ---------------------------------------------------------------------------
// Scatter + alpha: pos = offs[c] + rank[e]; pack {row, a01, a23} (16 B).
// ---------------------------------------------------------------------------
__global__ __launch_bounds__(256) void k_scatter_alpha(const int* __restrict__ rows,
                                                       const int* __restrict__ cols,
                                                       const int* __restrict__ offs,
                                                       const int* __restrict__ rank,
                                                       const float* __restrict__ d_i,
                                                       const float* __restrict__ d_j,
                                                       uint4* __restrict__ sorted,
                                                       int E, int N) {
    int e = blockIdx.x * blockDim.x + threadIdx.x;
    if (e >= E + N) return;
    int r, c;
    if (e < E) { r = rows[e]; c = cols[e]; }
    else       { r = e - E;   c = r; }
    int pos = offs[c] + rank[e];

    float4 di4 = *(const float4*)(d_i + (size_t)r * HEADS);
    float4 dj4 = *(const float4*)(d_j + (size_t)c * HEADS);
    float l0 = di4.x + dj4.x, l1 = di4.y + dj4.y;
    float l2 = di4.z + dj4.z, l3 = di4.w + dj4.w;
    l0 = l0 > 0.f ? l0 : NEG_SLOPE * l0;
    l1 = l1 > 0.f ? l1 : NEG_SLOPE * l1;
    l2 = l2 > 0.f ? l2 : NEG_SLOPE * l2;
    l3 = l3 > 0.f ? l3 : NEG_SLOPE * l3;
    float m = fmaxf(fmaxf(l0, l1), fmaxf(l2, l3));
    float e0 = __expf(l0 - m), e1 = __expf(l1 - m);
    float e2 = __expf(l2 - m), e3 = __expf(l3 - m);
    float inv = 1.f / (e0 + e1 + e2 + e3);

    uint32 p01 = bf16_rne(e0 * inv) | (bf16_rne(e1 * inv) << 16);
    uint32 p23 = bf16_rne(e2 * inv) | (bf16_rne(e3 * inv) << 16);
    sorted[pos] = make_uint4((uint32)r, p01, p23, 0u);
}

// ---------------------------------------------------------------------------
// Accumulate: one wave per dest node; vector-path record loads.
// ---------------------------------------------------------------------------
__global__ __launch_bounds__(256) void k_accum(const int* __restrict__ offs,
                                               const uint4* __restrict__ sorted,
                                               const u16* __restrict__ h_bf,
                                               const float* __restrict__ bias,
                                               float* __restrict__ out, int N) {
    int node = blockIdx.x * 4 + (threadIdx.x >> 6);
    if (node >= N) return;
    int c = __builtin_amdgcn_readfirstlane(node);
    int lane = threadIdx.x & 63;
    int head = lane >> 4;

    int s = offs[c], e = offs[c + 1];
    float acc = 0.f;
    int i = s;
    for (; i + 1 < e; i += 2) {
        int i0 = i, i1 = i + 1;
        asm volatile("" : "+v"(i0));
        asm volatile("" : "+v"(i1));
        uint4 v0 = sorted[i0];
        uint4 v1 = sorted[i1];
        uint32 p0 = (head & 2) ? v0.z : v0.y;
        uint32 p1 = (head & 2) ? v1.z : v1.y;
        float a0 = (head & 1) ? __uint_as_float(p0 & 0xffff0000u)
                              : __uint_as_float(p0 << 16);
        float a1 = (head & 1) ? __uint_as_float(p1 & 0xffff0000u)
                              : __uint_as_float(p1 << 16);
        u16 hb0 = h_bf[(size_t)v0.x * CCH + lane];
        u16 hb1 = h_bf[(size_t)v1.x * CCH + lane];
        acc = fmaf(__uint_as_float((uint32)hb0 << 16), a0, acc);
        acc = fmaf(__uint_as_float((uint32)hb1 << 16), a1, acc);
    }
    if (i < e) {
        int i0 = i;
        asm volatile("" : "+v"(i0));
        uint4 v0 = sorted[i0];
        uint32 p0 = (head & 2) ? v0.z : v0.y;
        float a0 = (head & 1) ? __uint_as_float(p0 & 0xffff0000u)
                              : __uint_as_float(p0 << 16);
        u16 hb0 = h_bf[(size_t)v0.x * CCH + lane];
        acc = fmaf(__uint_as_float((uint32)hb0 << 16), a0, acc);
    }
    out[(size_t)c * CCH + lane] = acc + bias[lane];
}

extern "C" void kernel_launch(void* const* d_in, const int* in_sizes, int n_in,
                              void* d_out, int out_size, void* d_ws, size_t ws_size,
                              hipStream_t stream) {
    const float* x    = (const float*)d_in[0];
    const int*   ei   = (const int*)  d_in[1];
    const float* w    = (const float*)d_in[2];
    const float* att  = (const float*)d_in[3];
    const float* bias = (const float*)d_in[4];
    float* out = (float*)d_out;

    int N = in_sizes[0] / IN_CH;
    int E = in_sizes[1] / 2;
    const int* rows = ei;
    const int* cols = ei + E;
    int total_e = E + N;
    int NB = (N + 1023) / 1024;
    int Npad = (N + 3) & ~3;

    char* ws = (char*)d_ws;
    auto carve = [&](size_t bytes) {
        char* p = ws;
        ws += (bytes + 255) & ~(size_t)255;
        return p;
    };
    u16*   h_bf   = (u16*)  carve((size_t)N * CCH * 2);          // 6.4 MB
    float* di     = (float*)carve((size_t)N * HEADS * 4);        // 0.8 MB
    float* dj     = (float*)carve((size_t)N * HEADS * 4);        // 0.8 MB
    int*   deg    = (int*)  carve((size_t)Npad * 4);
    int*   offs   = (int*)  carve((size_t)(N + 1) * 4);
    int*   parts  = (int*)  carve((size_t)(NB + 1) * 4);
    int*   rank   = (int*)  carve((size_t)total_e * 4);          // 3.4 MB
    uint4* sorted = (uint4*)carve((size_t)total_e * 16);         // 13.6 MB

    const int GEMM_BLOCKS = 768;                 // 3072 waves
    const int GEMM_WAVES  = GEMM_BLOCKS * 4;

    k_zero<<<(Npad + 255) / 256, 256, 0, stream>>>(deg, Npad);
    k_count_rank<<<(total_e + 255) / 256, 256, 0, stream>>>(cols, deg, rank, E, N);
    k_scan_blk<<<NB, 256, 0, stream>>>(deg, offs, parts, N);
    k_scan_part<<<1, 64, 0, stream>>>(parts, NB);
    k_scan_add<<<(N + 255) / 256, 256, 0, stream>>>(offs, parts, N, NB);
    gat_gemm_mfma<<<GEMM_BLOCKS, 256, 0, stream>>>(x, w, h_bf, N, GEMM_WAVES);
    k_dots<<<(N * HEADS + 255) / 256, 256, 0, stream>>>(h_bf, att, di, dj, N);
    k_scatter_alpha<<<(total_e + 255) / 256, 256, 0, stream>>>(rows, cols, offs, rank,
                                                               di, dj, sorted, E, N);
    k_accum<<<(N + 3) / 4, 256, 0, stream>>>(offs, sorted, h_bf, bias, out, N);
}